// Round 3
// baseline (1005.402 us; speedup 1.0000x reference)
//
#include <hip/hip_runtime.h>
#include <hip/hip_bf16.h>

typedef unsigned int u32;

// ---------------------------------------------------------------------------
// edge_index may be int64 (jax x64 enabled) or int32 (default jax demotion).
// Detect on device: for int64, the high 32-bit word of every element is 0.
// ---------------------------------------------------------------------------
__global__ void detect_i64_kernel(const u32* __restrict__ ei, u32* __restrict__ flag, int nchk)
{
    __shared__ u32 s_any;
    if (threadIdx.x == 0) s_any = 0u;
    __syncthreads();
    for (int i = threadIdx.x; i < nchk; i += blockDim.x)
        if (ei[2 * i + 1] != 0u) atomicOr(&s_any, 1u);
    __syncthreads();
    if (threadIdx.x == 0) *flag = (s_any ? 0u : 1u);   // 1 == int64 layout
}

__device__ __forceinline__ void load_edge(const void* ei, long long E, int e, int is64,
                                          u32& src, u32& dst)
{
    if (is64) {
        const unsigned long long* p = (const unsigned long long*)ei;
        src = (u32)p[e];
        dst = (u32)p[E + e];
    } else {
        const u32* p = (const u32*)ei;
        src = p[e];
        dst = p[E + e];
    }
}

// ---------------------------------------------------------------------------
// CSR build: degree histogram -> exclusive scan -> slot fill
// ---------------------------------------------------------------------------
__global__ __launch_bounds__(256) void count_kernel(const void* __restrict__ ei, long long E,
                                                    const u32* __restrict__ flag,
                                                    u32* __restrict__ deg)
{
    int e = blockIdx.x * 256 + threadIdx.x;
    if (e >= (int)E) return;
    int is64 = (int)flag[0];
    u32 src, dst;
    load_edge(ei, E, e, is64, src, dst);
    atomicAdd(&deg[dst], 1u);
}

__global__ __launch_bounds__(256) void scan_block_kernel(const u32* __restrict__ deg,
                                                         u32* __restrict__ rowptr,
                                                         u32* __restrict__ partial, int n)
{
    __shared__ u32 s[256];
    int t = threadIdx.x;
    int i = blockIdx.x * 256 + t;
    u32 v = (i < n) ? deg[i] : 0u;
    s[t] = v;
    __syncthreads();
    for (int off = 1; off < 256; off <<= 1) {
        u32 tmp = (t >= off) ? s[t - off] : 0u;
        __syncthreads();
        s[t] += tmp;
        __syncthreads();
    }
    if (i < n) rowptr[i] = s[t] - v;           // exclusive within block
    if (t == 255) partial[blockIdx.x] = s[255]; // block total
}

__global__ __launch_bounds__(512) void scan_partials_kernel(const u32* __restrict__ partial,
                                                            u32* __restrict__ pscan, int nb)
{
    __shared__ u32 s[512];
    int t = threadIdx.x;
    u32 v = (t < nb) ? partial[t] : 0u;
    s[t] = v;
    __syncthreads();
    for (int off = 1; off < 512; off <<= 1) {
        u32 tmp = (t >= off) ? s[t - off] : 0u;
        __syncthreads();
        s[t] += tmp;
        __syncthreads();
    }
    if (t < nb) pscan[t] = s[t] - v;           // exclusive across blocks
}

// also primes fillcnt = rowptr so fill_kernel skips the rowptr read
__global__ __launch_bounds__(256) void add_offsets_kernel(u32* __restrict__ rowptr,
                                                          const u32* __restrict__ pscan,
                                                          u32* __restrict__ fillcnt,
                                                          int n, u32 total)
{
    int i = blockIdx.x * 256 + threadIdx.x;
    if (i < n) {
        u32 v = rowptr[i] + pscan[blockIdx.x];
        rowptr[i] = v;
        fillcnt[i] = v;
    }
    if (i == 0) rowptr[n] = total;
}

__global__ __launch_bounds__(256) void fill_kernel(const void* __restrict__ ei, long long E,
                                                   const u32* __restrict__ flag,
                                                   u32* __restrict__ fillcnt,
                                                   u32* __restrict__ col)
{
    int e = blockIdx.x * 256 + threadIdx.x;
    if (e >= (int)E) return;
    int is64 = (int)flag[0];
    u32 src, dst;
    load_edge(ei, E, e, is64, src, dst);
    u32 pos = atomicAdd(&fillcnt[dst], 1u);
    col[pos] = src;
}

// ---------------------------------------------------------------------------
// Mean aggregation: one wave per dst node, split into two half-waves that
// each gather a FULL 512B row (32 lanes x float4) for alternating edges.
// 4 independent gathers in flight per half-wave; halves combined with
// __shfl_xor(32). No atomics; writes mean (pre-divided).
// ---------------------------------------------------------------------------
__global__ __launch_bounds__(256) void agg_kernel(const float* __restrict__ H,
                                                  const u32* __restrict__ col,
                                                  const u32* __restrict__ rowptr,
                                                  float* __restrict__ out, int n)
{
    const int wave = threadIdx.x >> 6;
    const int lane = threadIdx.x & 63;
    const int half = lane >> 5;       // 0: even edges, 1: odd edges
    const int l = lane & 31;          // column group: cols 4l..4l+3
    const int node = blockIdx.x * 4 + wave;
    if (node >= n) return;
    const u32 b0 = rowptr[node], b1 = rowptr[node + 1];
    float ax = 0.f, ay = 0.f, az = 0.f, aw = 0.f;
    u32 j = b0 + half;
    for (; j + 6 < b1; j += 8) {      // 4 stride-2 gathers in flight
        u32 s0 = col[j], s1 = col[j + 2], s2 = col[j + 4], s3 = col[j + 6];
        float4 v0 = *(const float4*)(H + (size_t)s0 * 128 + l * 4);
        float4 v1 = *(const float4*)(H + (size_t)s1 * 128 + l * 4);
        float4 v2 = *(const float4*)(H + (size_t)s2 * 128 + l * 4);
        float4 v3 = *(const float4*)(H + (size_t)s3 * 128 + l * 4);
        ax += v0.x; ay += v0.y; az += v0.z; aw += v0.w;
        ax += v1.x; ay += v1.y; az += v1.z; aw += v1.w;
        ax += v2.x; ay += v2.y; az += v2.z; aw += v2.w;
        ax += v3.x; ay += v3.y; az += v3.z; aw += v3.w;
    }
    for (; j < b1; j += 2) {
        u32 s0 = col[j];
        float4 v0 = *(const float4*)(H + (size_t)s0 * 128 + l * 4);
        ax += v0.x; ay += v0.y; az += v0.z; aw += v0.w;
    }
    // combine even/odd halves (lane l <-> lane l+32)
    ax += __shfl_xor(ax, 32);
    ay += __shfl_xor(ay, 32);
    az += __shfl_xor(az, 32);
    aw += __shfl_xor(aw, 32);
    if (half == 0) {
        const float inv = (b1 > b0) ? 1.0f / (float)(b1 - b0) : 1.0f;  // max(cnt,1)
        *(float4*)(out + (size_t)node * 128 + l * 4) =
            make_float4(ax * inv, ay * inv, az * inv, aw * inv);
    }
}

// ---------------------------------------------------------------------------
// Fused: out = prelu(M @ Wl^T + X @ Wr^T + bl, alpha), as ONE GEMM with
// fused K=256 over [M|X] x [Wl|Wr]. 128x128 tile, 8x8 acc per thread,
// K staged in 32-chunks. LDS layouts are k-major per row/col with an XOR
// swizzle on the float4 slot: offset(i,kk) = i*32 + ((kk>>2)^((i>>3)&7))*4,
// giving conflict-free ds_read_b128 for A (4 distinct rows/instr -> 4
// distinct slots) and 2-way (free) for W. LDS 32KB. No W transpose needed.
// Per 4 k-steps/thread: 16 ds_read_b128 (192cy) vs 512 FMA-cy -> ~73% VALU
// ceiling (old layout: ~52%, measured 55%).
// In-place safe (out==X): blocks read only their own rows (clamp stays in
// the last block's own range) and stores happen after all reads.
// ---------------------------------------------------------------------------
__global__ __launch_bounds__(256) void gemm_prelu_kernel(
    const float* __restrict__ M, const float* __restrict__ X,
    const float* __restrict__ Wl, const float* __restrict__ bl,
    const float* __restrict__ Wr, const float* __restrict__ al,
    float* __restrict__ out, int n)
{
    __shared__ float sA[128 * 32];
    __shared__ float sW[128 * 32];

    const int t = threadIdx.x;
    const int row0 = blockIdx.x * 128;
    const int r0 = (t >> 4) * 8;          // 16 row groups
    const int c0 = (t & 15) * 8;          // 16 col groups
    const int key_a = (t >> 4) & 7;
    const int key_w = t & 7;

    float acc[8][8];
#pragma unroll
    for (int r = 0; r < 8; ++r)
#pragma unroll
        for (int j = 0; j < 8; ++j) acc[r][j] = 0.f;

    // stage-loader mapping: f4 idx = t + 256q -> i = idx>>3 (row/col 0..127),
    // slot = idx&7 (k-float4 within 32-chunk)
    const int li = t >> 3;                 // base row/col for this thread
    const int lslot = t & 7;

#pragma unroll 1
    for (int ch = 0; ch < 8; ++ch) {
        const float* __restrict__ Asrc = (ch < 4) ? M : X;
        const float* __restrict__ Wsrc = (ch < 4) ? Wl : Wr;
        const int kc = (ch & 3) * 32;
        __syncthreads();
#pragma unroll
        for (int q = 0; q < 4; ++q) {
            const int i = li + q * 32;     // 0..127
            const int key = (i >> 3) & 7;
            int grow = row0 + i; if (grow > n - 1) grow = n - 1;
            const float4 va = *(const float4*)(Asrc + (size_t)grow * 128 + kc + lslot * 4);
            *(float4*)(sA + i * 32 + ((lslot ^ key) << 2)) = va;
            const float4 vw = *(const float4*)(Wsrc + (size_t)i * 128 + kc + lslot * 4);
            *(float4*)(sW + i * 32 + ((lslot ^ key) << 2)) = vw;
        }
        __syncthreads();

#pragma unroll 1
        for (int s = 0; s < 8; ++s) {      // k-float4 slot within the chunk
            float4 a[8], w[8];
            const int sa = (s ^ key_a) << 2;
            const int sw = (s ^ key_w) << 2;
#pragma unroll
            for (int r = 0; r < 8; ++r)
                a[r] = *(const float4*)(sA + (r0 + r) * 32 + sa);
#pragma unroll
            for (int j = 0; j < 8; ++j)
                w[j] = *(const float4*)(sW + (c0 + j) * 32 + sw);
#pragma unroll
            for (int r = 0; r < 8; ++r)
#pragma unroll
                for (int j = 0; j < 8; ++j) {
                    acc[r][j] += a[r].x * w[j].x;
                    acc[r][j] += a[r].y * w[j].y;
                    acc[r][j] += a[r].z * w[j].z;
                    acc[r][j] += a[r].w * w[j].w;
                }
        }
    }

    const float4 bv0 = *(const float4*)(bl + c0);
    const float4 bv1 = *(const float4*)(bl + c0 + 4);
    const float4 av0 = *(const float4*)(al + c0);
    const float4 av1 = *(const float4*)(al + c0 + 4);

#pragma unroll
    for (int r = 0; r < 8; ++r) {
        const int grow = row0 + r0 + r;
        if (grow < n) {
            float4 o0, o1;
            float v;
            v = acc[r][0] + bv0.x; o0.x = (v >= 0.f) ? v : av0.x * v;
            v = acc[r][1] + bv0.y; o0.y = (v >= 0.f) ? v : av0.y * v;
            v = acc[r][2] + bv0.z; o0.z = (v >= 0.f) ? v : av0.z * v;
            v = acc[r][3] + bv0.w; o0.w = (v >= 0.f) ? v : av0.w * v;
            v = acc[r][4] + bv1.x; o1.x = (v >= 0.f) ? v : av1.x * v;
            v = acc[r][5] + bv1.y; o1.y = (v >= 0.f) ? v : av1.y * v;
            v = acc[r][6] + bv1.z; o1.z = (v >= 0.f) ? v : av1.z * v;
            v = acc[r][7] + bv1.w; o1.w = (v >= 0.f) ? v : av1.w * v;
            *(float4*)(out + (size_t)grow * 128 + c0) = o0;
            *(float4*)(out + (size_t)grow * 128 + c0 + 4) = o1;
        }
    }
}

// ---------------------------------------------------------------------------
extern "C" void kernel_launch(void* const* d_in, const int* in_sizes, int n_in,
                              void* d_out, int out_size, void* d_ws, size_t ws_size,
                              hipStream_t stream)
{
    const float* x   = (const float*)d_in[0];
    const void*  ei  = d_in[1];
    const float* Wl1 = (const float*)d_in[2],  *bl1 = (const float*)d_in[3];
    const float* Wr1 = (const float*)d_in[4],  *a1  = (const float*)d_in[5];
    const float* Wl2 = (const float*)d_in[6],  *bl2 = (const float*)d_in[7];
    const float* Wr2 = (const float*)d_in[8],  *a2  = (const float*)d_in[9];
    const float* Wl3 = (const float*)d_in[10], *bl3 = (const float*)d_in[11];
    const float* Wr3 = (const float*)d_in[12], *a3  = (const float*)d_in[13];
    float* out = (float*)d_out;

    const int       N = in_sizes[0] / 128;
    const long long E = in_sizes[1] / 2;

    // bump allocator over d_ws (needs ~60 MB)
    char* p = (char*)d_ws;
    auto alloc = [&](size_t bytes) {
        char* r = p;
        p += (bytes + 255) & ~(size_t)255;
        return (void*)r;
    };
    u32* deg     = (u32*)alloc((size_t)N * 4);
    u32* rowptr  = (u32*)alloc(((size_t)N + 1) * 4);
    u32* fillcnt = (u32*)alloc((size_t)N * 4);
    u32* partial = (u32*)alloc(512 * 4);
    u32* pscan   = (u32*)alloc(512 * 4);
    u32* flag    = (u32*)alloc(256);
    u32* col     = (u32*)alloc((size_t)E * 4);
    float* aggb  = (float*)alloc((size_t)N * 128 * 4);

    hipMemsetAsync(deg, 0, (size_t)N * 4, stream);

    detect_i64_kernel<<<1, 256, 0, stream>>>((const u32*)ei, flag, 2048);

    const int eblocks = (int)((E + 255) / 256);
    const int nb      = (N + 255) / 256;

    count_kernel<<<eblocks, 256, 0, stream>>>(ei, E, flag, deg);
    scan_block_kernel<<<nb, 256, 0, stream>>>(deg, rowptr, partial, N);
    scan_partials_kernel<<<1, 512, 0, stream>>>(partial, pscan, nb);
    add_offsets_kernel<<<nb, 256, 0, stream>>>(rowptr, pscan, fillcnt, N, (u32)E);
    fill_kernel<<<eblocks, 256, 0, stream>>>(ei, E, flag, fillcnt, col);

    const int ablocks = (N + 3) / 4;
    const int gblocks = (N + 127) / 128;

    // layer 1: x -> d_out
    agg_kernel<<<ablocks, 256, 0, stream>>>(x, col, rowptr, aggb, N);
    gemm_prelu_kernel<<<gblocks, 256, 0, stream>>>(aggb, x, Wl1, bl1, Wr1, a1, out, N);
    // layer 2: d_out -> d_out (in-place GEMM is safe: blocks touch only own rows)
    agg_kernel<<<ablocks, 256, 0, stream>>>(out, col, rowptr, aggb, N);
    gemm_prelu_kernel<<<gblocks, 256, 0, stream>>>(aggb, out, Wl2, bl2, Wr2, a2, out, N);
    // layer 3: d_out -> d_out
    agg_kernel<<<ablocks, 256, 0, stream>>>(out, col, rowptr, aggb, N);
    gemm_prelu_kernel<<<gblocks, 256, 0, stream>>>(aggb, out, Wl3, bl3, Wr3, a3, out, N);
}

// Round 4
// 765.110 us; speedup vs baseline: 1.3141x; 1.3141x over previous
//
#include <hip/hip_runtime.h>
#include <hip/hip_bf16.h>

typedef unsigned int u32;
typedef unsigned short u16;
typedef __attribute__((ext_vector_type(8))) short s16x8;
typedef __attribute__((ext_vector_type(4))) float f32x4;

// ---------------------------------------------------------------------------
// edge_index may be int64 (jax x64 enabled) or int32 (default jax demotion).
// ---------------------------------------------------------------------------
__global__ void detect_i64_kernel(const u32* __restrict__ ei, u32* __restrict__ flag, int nchk)
{
    __shared__ u32 s_any;
    if (threadIdx.x == 0) s_any = 0u;
    __syncthreads();
    for (int i = threadIdx.x; i < nchk; i += blockDim.x)
        if (ei[2 * i + 1] != 0u) atomicOr(&s_any, 1u);
    __syncthreads();
    if (threadIdx.x == 0) *flag = (s_any ? 0u : 1u);   // 1 == int64 layout
}

__device__ __forceinline__ void load_edge(const void* ei, long long E, int e, int is64,
                                          u32& src, u32& dst)
{
    if (is64) {
        const unsigned long long* p = (const unsigned long long*)ei;
        src = (u32)p[e];
        dst = (u32)p[E + e];
    } else {
        const u32* p = (const u32*)ei;
        src = p[e];
        dst = p[E + e];
    }
}

// ---------------------------------------------------------------------------
// CSR build: degree histogram -> exclusive scan -> slot fill
// ---------------------------------------------------------------------------
__global__ __launch_bounds__(256) void count_kernel(const void* __restrict__ ei, long long E,
                                                    const u32* __restrict__ flag,
                                                    u32* __restrict__ deg)
{
    int e = blockIdx.x * 256 + threadIdx.x;
    if (e >= (int)E) return;
    int is64 = (int)flag[0];
    u32 src, dst;
    load_edge(ei, E, e, is64, src, dst);
    atomicAdd(&deg[dst], 1u);
}

__global__ __launch_bounds__(256) void scan_block_kernel(const u32* __restrict__ deg,
                                                         u32* __restrict__ rowptr,
                                                         u32* __restrict__ partial, int n)
{
    __shared__ u32 s[256];
    int t = threadIdx.x;
    int i = blockIdx.x * 256 + t;
    u32 v = (i < n) ? deg[i] : 0u;
    s[t] = v;
    __syncthreads();
    for (int off = 1; off < 256; off <<= 1) {
        u32 tmp = (t >= off) ? s[t - off] : 0u;
        __syncthreads();
        s[t] += tmp;
        __syncthreads();
    }
    if (i < n) rowptr[i] = s[t] - v;           // exclusive within block
    if (t == 255) partial[blockIdx.x] = s[255]; // block total
}

__global__ __launch_bounds__(512) void scan_partials_kernel(const u32* __restrict__ partial,
                                                            u32* __restrict__ pscan, int nb)
{
    __shared__ u32 s[512];
    int t = threadIdx.x;
    u32 v = (t < nb) ? partial[t] : 0u;
    s[t] = v;
    __syncthreads();
    for (int off = 1; off < 512; off <<= 1) {
        u32 tmp = (t >= off) ? s[t - off] : 0u;
        __syncthreads();
        s[t] += tmp;
        __syncthreads();
    }
    if (t < nb) pscan[t] = s[t] - v;           // exclusive across blocks
}

// also primes fillcnt = rowptr so fill_kernel skips the rowptr read
__global__ __launch_bounds__(256) void add_offsets_kernel(u32* __restrict__ rowptr,
                                                          const u32* __restrict__ pscan,
                                                          u32* __restrict__ fillcnt,
                                                          int n, u32 total)
{
    int i = blockIdx.x * 256 + threadIdx.x;
    if (i < n) {
        u32 v = rowptr[i] + pscan[blockIdx.x];
        rowptr[i] = v;
        fillcnt[i] = v;
    }
    if (i == 0) rowptr[n] = total;
}

__global__ __launch_bounds__(256) void fill_kernel(const void* __restrict__ ei, long long E,
                                                   const u32* __restrict__ flag,
                                                   u32* __restrict__ fillcnt,
                                                   u32* __restrict__ col)
{
    int e = blockIdx.x * 256 + threadIdx.x;
    if (e >= (int)E) return;
    int is64 = (int)flag[0];
    u32 src, dst;
    load_edge(ei, E, e, is64, src, dst);
    u32 pos = atomicAdd(&fillcnt[dst], 1u);
    col[pos] = src;
}

// ---------------------------------------------------------------------------
// Mean aggregation: one wave per dst node, two half-waves gather alternating
// edges as full 512B rows (32 lanes x float4); combined via __shfl_xor(32).
// ---------------------------------------------------------------------------
__global__ __launch_bounds__(256) void agg_kernel(const float* __restrict__ H,
                                                  const u32* __restrict__ col,
                                                  const u32* __restrict__ rowptr,
                                                  float* __restrict__ out, int n)
{
    const int wave = threadIdx.x >> 6;
    const int lane = threadIdx.x & 63;
    const int half = lane >> 5;       // 0: even edges, 1: odd edges
    const int l = lane & 31;          // column group: cols 4l..4l+3
    const int node = blockIdx.x * 4 + wave;
    if (node >= n) return;
    const u32 b0 = rowptr[node], b1 = rowptr[node + 1];
    float ax = 0.f, ay = 0.f, az = 0.f, aw = 0.f;
    u32 j = b0 + half;
    for (; j + 6 < b1; j += 8) {      // 4 stride-2 gathers in flight
        u32 s0 = col[j], s1 = col[j + 2], s2 = col[j + 4], s3 = col[j + 6];
        float4 v0 = *(const float4*)(H + (size_t)s0 * 128 + l * 4);
        float4 v1 = *(const float4*)(H + (size_t)s1 * 128 + l * 4);
        float4 v2 = *(const float4*)(H + (size_t)s2 * 128 + l * 4);
        float4 v3 = *(const float4*)(H + (size_t)s3 * 128 + l * 4);
        ax += v0.x; ay += v0.y; az += v0.z; aw += v0.w;
        ax += v1.x; ay += v1.y; az += v1.z; aw += v1.w;
        ax += v2.x; ay += v2.y; az += v2.z; aw += v2.w;
        ax += v3.x; ay += v3.y; az += v3.z; aw += v3.w;
    }
    for (; j < b1; j += 2) {
        u32 s0 = col[j];
        float4 v0 = *(const float4*)(H + (size_t)s0 * 128 + l * 4);
        ax += v0.x; ay += v0.y; az += v0.z; aw += v0.w;
    }
    ax += __shfl_xor(ax, 32);
    ay += __shfl_xor(ay, 32);
    az += __shfl_xor(az, 32);
    aw += __shfl_xor(aw, 32);
    if (half == 0) {
        const float inv = (b1 > b0) ? 1.0f / (float)(b1 - b0) : 1.0f;  // max(cnt,1)
        *(float4*)(out + (size_t)node * 128 + l * 4) =
            make_float4(ax * inv, ay * inv, az * inv, aw * inv);
    }
}

// ---------------------------------------------------------------------------
// bf16 split helpers (RNE)
// ---------------------------------------------------------------------------
__device__ __forceinline__ u16 f32_to_bf16_rne(float f)
{
    u32 u = __float_as_uint(f);
    return (u16)((u + 0x7FFFu + ((u >> 16) & 1u)) >> 16);
}
__device__ __forceinline__ float bf16_bits_to_f32(u16 h)
{
    return __uint_as_float(((u32)h) << 16);
}

// Pre-split the 6 weight matrices (fp32 [128c x 128k]) into bf16 hi/lo pairs.
__global__ __launch_bounds__(256) void wsplit_kernel(
    const float* __restrict__ s0, const float* __restrict__ s1, const float* __restrict__ s2,
    const float* __restrict__ s3, const float* __restrict__ s4, const float* __restrict__ s5,
    u16* __restrict__ h0, u16* __restrict__ l0, u16* __restrict__ h1, u16* __restrict__ l1,
    u16* __restrict__ h2, u16* __restrict__ l2, u16* __restrict__ h3, u16* __restrict__ l3,
    u16* __restrict__ h4, u16* __restrict__ l4, u16* __restrict__ h5, u16* __restrict__ l5,
    int nelem)
{
    const float* s; u16* h; u16* l;
    switch (blockIdx.y) {
        case 0: s = s0; h = h0; l = l0; break;
        case 1: s = s1; h = h1; l = l1; break;
        case 2: s = s2; h = h2; l = l2; break;
        case 3: s = s3; h = h3; l = l3; break;
        case 4: s = s4; h = h4; l = l4; break;
        default: s = s5; h = h5; l = l5; break;
    }
    int i = blockIdx.x * 256 + threadIdx.x;
    if (i >= nelem) return;
    float f = s[i];
    u16 hb = f32_to_bf16_rne(f);
    u16 lb = f32_to_bf16_rne(f - bf16_bits_to_f32(hb));
    h[i] = hb;
    l[i] = lb;
}

// ---------------------------------------------------------------------------
// MFMA GEMM: out = prelu(M @ Wl^T + X @ Wr^T + bl, alpha) in fp32, computed
// via bf16 3-product split (Ah*Wh + Ah*Wl + Al*Wh, err ~2^-17).
// 128x128 C-tile / block, 4 waves each owning a 64x64 sub-tile, MFMA
// 16x16x32 bf16 (A/B frag: idx=lane&15, k=(lane>>4)*8+j; C/D: col=lane&15,
// row=(lane>>4)*4+reg). A (fp32) is split to hi/lo during staging; W comes
// pre-split. LDS tiles [128][32] bf16 (64B row stride): frag reads hit quad
// 4*(row&1)+chunk -> 8 lanes/quad, distinct addrs = conflict-free; staging
// writes are linear 16B granules = conflict-free. No swizzle (R3 lesson:
// slot-XOR with bank-aligned row stride creates conflicts, don't).
// In-place safe (out==X): blocks only read rows they write; all staging
// reads precede the epilogue stores (barrier-ordered within the block).
// ---------------------------------------------------------------------------
__global__ __launch_bounds__(256) void gemm_mfma_kernel(
    const float* __restrict__ M, const float* __restrict__ X,
    const u16* __restrict__ Whl, const u16* __restrict__ Wll,
    const u16* __restrict__ Whr, const u16* __restrict__ Wlr,
    const float* __restrict__ bl, const float* __restrict__ al,
    float* __restrict__ out, int n)
{
    __shared__ u16 sAh[128 * 32];
    __shared__ u16 sAl[128 * 32];
    __shared__ u16 sWh[128 * 32];
    __shared__ u16 sWl[128 * 32];

    const int t = threadIdx.x;
    const int lane = t & 63;
    const int wv = t >> 6;
    const int wm = wv >> 1, wn = wv & 1;
    const int row0 = blockIdx.x * 128;

    f32x4 acc[4][4];
#pragma unroll
    for (int a = 0; a < 4; ++a)
#pragma unroll
        for (int b = 0; b < 4; ++b) acc[a][b] = (f32x4)0.f;

    float bcol[4], acol[4];
#pragma unroll
    for (int nf = 0; nf < 4; ++nf) {
        int c = wn * 64 + nf * 16 + (lane & 15);
        bcol[nf] = bl[c];
        acol[nf] = al[c];
    }

#pragma unroll 1
    for (int ch = 0; ch < 8; ++ch) {
        const float* __restrict__ Asrc = (ch < 4) ? M : X;
        const u16* __restrict__ Whs = (ch < 4) ? Whl : Whr;
        const u16* __restrict__ Wls = (ch < 4) ? Wll : Wlr;
        const int kc = (ch & 3) * 32;
        __syncthreads();
        // ---- A staging: fp32 -> bf16 hi/lo, 16B granules, linear LDS ----
#pragma unroll
        for (int q = 0; q < 2; ++q) {
            const int g = t + q * 256;            // granule 0..511
            const int row = g >> 2, k0 = (g & 3) * 8;
            int grow = row0 + row; if (grow > n - 1) grow = n - 1;
            const float4 f0 = *(const float4*)(Asrc + (size_t)grow * 128 + kc + k0);
            const float4 f1 = *(const float4*)(Asrc + (size_t)grow * 128 + kc + k0 + 4);
            float fv0 = f0.x, fv1 = f0.y, fv2 = f0.z, fv3 = f0.w;
            float fv4 = f1.x, fv5 = f1.y, fv6 = f1.z, fv7 = f1.w;
            s16x8 hv, lv;
            u16 hb;
            hb = f32_to_bf16_rne(fv0); hv[0] = (short)hb; lv[0] = (short)f32_to_bf16_rne(fv0 - bf16_bits_to_f32(hb));
            hb = f32_to_bf16_rne(fv1); hv[1] = (short)hb; lv[1] = (short)f32_to_bf16_rne(fv1 - bf16_bits_to_f32(hb));
            hb = f32_to_bf16_rne(fv2); hv[2] = (short)hb; lv[2] = (short)f32_to_bf16_rne(fv2 - bf16_bits_to_f32(hb));
            hb = f32_to_bf16_rne(fv3); hv[3] = (short)hb; lv[3] = (short)f32_to_bf16_rne(fv3 - bf16_bits_to_f32(hb));
            hb = f32_to_bf16_rne(fv4); hv[4] = (short)hb; lv[4] = (short)f32_to_bf16_rne(fv4 - bf16_bits_to_f32(hb));
            hb = f32_to_bf16_rne(fv5); hv[5] = (short)hb; lv[5] = (short)f32_to_bf16_rne(fv5 - bf16_bits_to_f32(hb));
            hb = f32_to_bf16_rne(fv6); hv[6] = (short)hb; lv[6] = (short)f32_to_bf16_rne(fv6 - bf16_bits_to_f32(hb));
            hb = f32_to_bf16_rne(fv7); hv[7] = (short)hb; lv[7] = (short)f32_to_bf16_rne(fv7 - bf16_bits_to_f32(hb));
            *(s16x8*)(sAh + g * 8) = hv;
            *(s16x8*)(sAl + g * 8) = lv;
        }
        // ---- W staging: pre-split bf16, straight 16B copies ----
#pragma unroll
        for (int q = 0; q < 2; ++q) {
            const int g = t + q * 256;
            const int c = g >> 2, k0 = (g & 3) * 8;
            *(s16x8*)(sWh + g * 8) = *(const s16x8*)(Whs + c * 128 + kc + k0);
            *(s16x8*)(sWl + g * 8) = *(const s16x8*)(Wls + c * 128 + kc + k0);
        }
        __syncthreads();

        // ---- fragments + MFMA ----
        const int lr = lane & 15, lk = (lane >> 4) * 8;
        s16x8 ah[4], alo[4], wh[4], wlo[4];
#pragma unroll
        for (int f = 0; f < 4; ++f) {
            const int ar = wm * 64 + f * 16 + lr;
            ah[f]  = *(const s16x8*)(sAh + ar * 32 + lk);
            alo[f] = *(const s16x8*)(sAl + ar * 32 + lk);
            const int wc_ = wn * 64 + f * 16 + lr;
            wh[f]  = *(const s16x8*)(sWh + wc_ * 32 + lk);
            wlo[f] = *(const s16x8*)(sWl + wc_ * 32 + lk);
        }
#pragma unroll
        for (int mf = 0; mf < 4; ++mf)
#pragma unroll
            for (int nf = 0; nf < 4; ++nf) {
                acc[mf][nf] = __builtin_amdgcn_mfma_f32_16x16x32_bf16(ah[mf],  wh[nf],  acc[mf][nf], 0, 0, 0);
                acc[mf][nf] = __builtin_amdgcn_mfma_f32_16x16x32_bf16(ah[mf],  wlo[nf], acc[mf][nf], 0, 0, 0);
                acc[mf][nf] = __builtin_amdgcn_mfma_f32_16x16x32_bf16(alo[mf], wh[nf],  acc[mf][nf], 0, 0, 0);
            }
    }

    // ---- epilogue: bias + PReLU, fp32 store ----
#pragma unroll
    for (int mf = 0; mf < 4; ++mf)
#pragma unroll
        for (int j = 0; j < 4; ++j) {
            const int row = row0 + wm * 64 + mf * 16 + (lane >> 4) * 4 + j;
            if (row < n) {
#pragma unroll
                for (int nf = 0; nf < 4; ++nf) {
                    float v = acc[mf][nf][j] + bcol[nf];
                    v = (v >= 0.f) ? v : acol[nf] * v;
                    out[(size_t)row * 128 + wn * 64 + nf * 16 + (lane & 15)] = v;
                }
            }
        }
}

// ---------------------------------------------------------------------------
extern "C" void kernel_launch(void* const* d_in, const int* in_sizes, int n_in,
                              void* d_out, int out_size, void* d_ws, size_t ws_size,
                              hipStream_t stream)
{
    const float* x   = (const float*)d_in[0];
    const void*  ei  = d_in[1];
    const float* Wl1 = (const float*)d_in[2],  *bl1 = (const float*)d_in[3];
    const float* Wr1 = (const float*)d_in[4],  *a1  = (const float*)d_in[5];
    const float* Wl2 = (const float*)d_in[6],  *bl2 = (const float*)d_in[7];
    const float* Wr2 = (const float*)d_in[8],  *a2  = (const float*)d_in[9];
    const float* Wl3 = (const float*)d_in[10], *bl3 = (const float*)d_in[11];
    const float* Wr3 = (const float*)d_in[12], *a3  = (const float*)d_in[13];
    float* out = (float*)d_out;

    const int       N = in_sizes[0] / 128;
    const long long E = in_sizes[1] / 2;
    const int       WN = 128 * 128;      // weight elements per matrix

    // bump allocator over d_ws (~60 MB)
    char* p = (char*)d_ws;
    auto alloc = [&](size_t bytes) {
        char* r = p;
        p += (bytes + 255) & ~(size_t)255;
        return (void*)r;
    };
    u32* deg     = (u32*)alloc((size_t)N * 4);
    u32* rowptr  = (u32*)alloc(((size_t)N + 1) * 4);
    u32* fillcnt = (u32*)alloc((size_t)N * 4);
    u32* partial = (u32*)alloc(512 * 4);
    u32* pscan   = (u32*)alloc(512 * 4);
    u32* flag    = (u32*)alloc(256);
    u32* col     = (u32*)alloc((size_t)E * 4);
    float* aggb  = (float*)alloc((size_t)N * 128 * 4);
    u16* wh[6]; u16* wl[6];
    for (int i = 0; i < 6; ++i) {
        wh[i] = (u16*)alloc((size_t)WN * 2);
        wl[i] = (u16*)alloc((size_t)WN * 2);
    }

    hipMemsetAsync(deg, 0, (size_t)N * 4, stream);

    detect_i64_kernel<<<1, 256, 0, stream>>>((const u32*)ei, flag, 2048);

    // weight split (independent of CSR chain)
    wsplit_kernel<<<dim3((WN + 255) / 256, 6), 256, 0, stream>>>(
        Wl1, Wr1, Wl2, Wr2, Wl3, Wr3,
        wh[0], wl[0], wh[1], wl[1], wh[2], wl[2],
        wh[3], wl[3], wh[4], wl[4], wh[5], wl[5], WN);

    const int eblocks = (int)((E + 255) / 256);
    const int nb      = (N + 255) / 256;

    count_kernel<<<eblocks, 256, 0, stream>>>(ei, E, flag, deg);
    scan_block_kernel<<<nb, 256, 0, stream>>>(deg, rowptr, partial, N);
    scan_partials_kernel<<<1, 512, 0, stream>>>(partial, pscan, nb);
    add_offsets_kernel<<<nb, 256, 0, stream>>>(rowptr, pscan, fillcnt, N, (u32)E);
    fill_kernel<<<eblocks, 256, 0, stream>>>(ei, E, flag, fillcnt, col);

    const int ablocks = (N + 3) / 4;
    const int gblocks = (N + 127) / 128;

    // layer 1: x -> d_out
    agg_kernel<<<ablocks, 256, 0, stream>>>(x, col, rowptr, aggb, N);
    gemm_mfma_kernel<<<gblocks, 256, 0, stream>>>(aggb, x, wh[0], wl[0], wh[1], wl[1],
                                                  bl1, a1, out, N);
    // layer 2: d_out -> d_out
    agg_kernel<<<ablocks, 256, 0, stream>>>(out, col, rowptr, aggb, N);
    gemm_mfma_kernel<<<gblocks, 256, 0, stream>>>(aggb, out, wh[2], wl[2], wh[3], wl[3],
                                                  bl2, a2, out, N);
    // layer 3: d_out -> d_out
    agg_kernel<<<ablocks, 256, 0, stream>>>(out, col, rowptr, aggb, N);
    gemm_mfma_kernel<<<gblocks, 256, 0, stream>>>(aggb, out, wh[4], wl[4], wh[5], wl[5],
                                                  bl3, a3, out, N);
}